// Round 3
// baseline (1031.659 us; speedup 1.0000x reference)
//
#include <hip/hip_runtime.h>
#include <float.h>

// Viterbi decode: B=1024, T=1024, K=48.
// Forward: TWO waves per b (block=128, grid=1024 -> 2048 waves = 2/SIMD for
//   latency hiding). Lane = next-tag; wave w computes partial argmax over
//   prevs [w*24, w*24+24) (24x{add,max,cmp,sel} per step), partials merged
//   via LDS with exact first-index ties (half0 wins ties). Wave0 writes fv,
//   wave1 writes bptr. Transition half-row resident in VGPRs.
// Backward: chunked scan (3 passes) as in R1 (exact).

#define BB 1024
#define TT 1024
#define KK 48
#define KH 24   // prevs per wave
#define CC 16   // chunks per sequence
#define LL 64   // steps per chunk
#define NEGV -10000.0f

__global__ __launch_bounds__(128, 1) void viterbi_fwd(
    const float* __restrict__ feats, const float* __restrict__ trans,
    float* __restrict__ scores, unsigned char* __restrict__ bptr,
    int* __restrict__ bestArr) {
  __shared__ __align__(16) float fvbuf[64];
  __shared__ float pval[2][64];
  __shared__ int pidx[2][64];
  const int lane = threadIdx.x & 63;
  const int w = threadIdx.x >> 6;
  const int b = blockIdx.x;
  const int rl = (lane < KK) ? lane : (KK - 1);
  const int wbase = w * KH;

  // This wave's half of the transition row: trans[next=rl][wbase..wbase+23].
  float tr[KH];
  {
    const float* trow = trans + rl * KK + wbase;
#pragma unroll
    for (int j = 0; j < 6; ++j) {
      float4 t4 = *(const float4*)(trow + 4 * j);
      tr[4 * j + 0] = t4.x; tr[4 * j + 1] = t4.y;
      tr[4 * j + 2] = t4.z; tr[4 * j + 3] = t4.w;
    }
  }
  const float tstop = trans[(KK - 1) * KK + rl];

  if (threadIdx.x < KK) fvbuf[threadIdx.x] = (threadIdx.x == 46) ? 0.0f : NEGV;
  __syncthreads();

  const float* fp = feats + (size_t)b * TT * KK;
  unsigned char* bp = bptr + (size_t)b * TT * KK;

  // feat prefetch ring (wave 0 only), distance 4
  float fbuf[4];
  if (w == 0) {
#pragma unroll
    for (int k = 0; k < 4; ++k) fbuf[k] = fp[(size_t)k * KK + rl];
  }

  float fv = NEGV;  // wave0's tracked forward var
  for (int t0 = 0; t0 < TT; t0 += 4) {
#pragma unroll
    for (int u = 0; u < 4; ++u) {
      const int t = t0 + u;
      // read this wave's half of fv (broadcast LDS reads)
      float fvr[KH];
      {
        const float* fh = fvbuf + wbase;
#pragma unroll
        for (int j = 0; j < 6; ++j) {
          float4 v4 = *(const float4*)(fh + 4 * j);
          fvr[4 * j + 0] = v4.x; fvr[4 * j + 1] = v4.y;
          fvr[4 * j + 2] = v4.z; fvr[4 * j + 3] = v4.w;
        }
      }

      // 4 independent chains of 6 (local indices 0..23, ascending; exact
      // first-index ties: within chain strict >, across chains take later
      // only on strict >).
      float bs0 = fvr[0] + tr[0], bs1 = fvr[6] + tr[6];
      float bs2 = fvr[12] + tr[12], bs3 = fvr[18] + tr[18];
      int bi0 = 0, bi1 = 6, bi2 = 12, bi3 = 18;
#pragma unroll
      for (int p = 1; p < 6; ++p) {
        float s0 = fvr[p] + tr[p];
        float s1 = fvr[6 + p] + tr[6 + p];
        float s2 = fvr[12 + p] + tr[12 + p];
        float s3 = fvr[18 + p] + tr[18 + p];
        if (s0 > bs0) { bs0 = s0; bi0 = p; }
        if (s1 > bs1) { bs1 = s1; bi1 = 6 + p; }
        if (s2 > bs2) { bs2 = s2; bi2 = 12 + p; }
        if (s3 > bs3) { bs3 = s3; bi3 = 18 + p; }
      }
      bool c1 = bs1 > bs0;
      float m01 = c1 ? bs1 : bs0; int i01 = c1 ? bi1 : bi0;
      bool c3 = bs3 > bs2;
      float m23 = c3 ? bs3 : bs2; int i23 = c3 ? bi3 : bi2;
      bool cf = m23 > m01;
      float bs = cf ? m23 : m01;
      int bpi = (cf ? i23 : i01) + wbase;  // global prev index

      pval[w][lane] = bs;
      pidx[w][lane] = bpi;
      __syncthreads();

      if (w == 0) {
        // merge (half0 wins ties), update fv, write fvbuf
        float ov = pval[1][lane]; int oi = pidx[1][lane];
        bool take = ov > bs;
        float m = take ? ov : bs;
        float nfv = m + fbuf[u];
        // prefetch feat for t+4 (uniform clamped offset)
        int tpre = (t + 4 < TT) ? (t + 4) : 0;
        fbuf[u] = fp[(size_t)tpre * KK + rl];
        if (lane < KK) { fvbuf[lane] = nfv; fv = nfv; }
      } else {
        // merge (same rule) and store backpointer byte
        float ov = pval[0][lane]; int oi = pidx[0][lane];
        bool keep_own = bs > ov;  // own = half1, wins only on strict >
        int bfinal = keep_own ? bpi : oi;
        if (lane < KK) bp[(size_t)t * KK + lane] = (unsigned char)bfinal;
      }
      __syncthreads();
    }
  }

  if (w == 0) {
    // terminal = F_T + transitions[STOP]; first-index argmax via butterfly
    float v = (lane < KK) ? (fv + tstop) : -FLT_MAX;
    int idx = lane;
#pragma unroll
    for (int off = 32; off >= 1; off >>= 1) {
      float ov = __shfl_xor(v, off);
      int oi = __shfl_xor(idx, off);
      bool take = (ov > v) || (ov == v && oi < idx);
      v = take ? ov : v;
      idx = take ? oi : idx;
    }
    if (lane == 0) {
      scores[b] = v;
      bestArr[b] = idx;
    }
  }
}

// Pass 1: composed tag map per (b, chunk).
__global__ __launch_bounds__(256) void bwd_map(
    const unsigned char* __restrict__ bptr, unsigned char* __restrict__ cmap) {
  const int lane = threadIdx.x & 63;
  const int wg = blockIdx.x * 4 + (threadIdx.x >> 6);
  const int b = wg >> 4;
  const int c = wg & (CC - 1);
  const int rl = (lane < KK) ? lane : (KK - 1);
  const unsigned char* bp = bptr + ((size_t)b * TT + (size_t)c * LL) * KK + rl;

  int x = rl;
  const int CH = 16;
  int cur[CH], nxt[CH];
#pragma unroll
  for (int j = 0; j < CH; ++j) cur[j] = bp[(size_t)(LL - CH + j) * KK];
  for (int tb = LL - CH; tb >= 0; tb -= CH) {
    if (tb >= CH) {
#pragma unroll
      for (int j = 0; j < CH; ++j) nxt[j] = bp[(size_t)(tb - CH + j) * KK];
    }
#pragma unroll
    for (int j = CH - 1; j >= 0; --j) x = __shfl(cur[j], x);
    if (tb >= CH) {
#pragma unroll
      for (int j = 0; j < CH; ++j) cur[j] = nxt[j];
    }
  }
  if (lane < KK) cmap[(size_t)wg * KK + lane] = (unsigned char)x;
}

// Pass 2: per-b compose over chunk maps -> entry tag per chunk.
__global__ __launch_bounds__(256) void bwd_entry(
    const unsigned char* __restrict__ cmap, const int* __restrict__ bestArr,
    int* __restrict__ entry) {
  const int lane = threadIdx.x & 63;
  const int b = blockIdx.x * 4 + (threadIdx.x >> 6);
  const int rl = (lane < KK) ? lane : (KK - 1);

  int rows[CC];
#pragma unroll
  for (int c = 0; c < CC; ++c) rows[c] = cmap[((size_t)b * CC + c) * KK + rl];

  int tag = bestArr[b];
  int ev = 0;
#pragma unroll
  for (int c = CC - 1; c >= 0; --c) {
    if (lane == c) ev = tag;
    tag = __shfl(rows[c], tag);
  }
  if (lane < CC) entry[b * CC + lane] = ev;
}

// Pass 3: re-walk chunk with known entry tag, coalesced emit.
__global__ __launch_bounds__(256) void bwd_emit(
    const unsigned char* __restrict__ bptr, const int* __restrict__ entry,
    float* __restrict__ path) {
  const int lane = threadIdx.x & 63;
  const int wg = blockIdx.x * 4 + (threadIdx.x >> 6);
  const int b = wg >> 4;
  const int c = wg & (CC - 1);
  const int rl = (lane < KK) ? lane : (KK - 1);
  const unsigned char* bp = bptr + ((size_t)b * TT + (size_t)c * LL) * KK + rl;

  int x = entry[b * CC + c];
  int myv = 0;
  const int CH = 16;
  int cur[CH], nxt[CH];
#pragma unroll
  for (int j = 0; j < CH; ++j) cur[j] = bp[(size_t)(LL - CH + j) * KK];
  for (int tb = LL - CH; tb >= 0; tb -= CH) {
    if (tb >= CH) {
#pragma unroll
      for (int j = 0; j < CH; ++j) nxt[j] = bp[(size_t)(tb - CH + j) * KK];
    }
#pragma unroll
    for (int j = CH - 1; j >= 0; --j) {
      if (lane == tb + j) myv = x;
      x = __shfl(cur[j], x);
    }
    if (tb >= CH) {
#pragma unroll
      for (int j = 0; j < CH; ++j) cur[j] = nxt[j];
    }
  }
  path[(size_t)b * TT + (size_t)c * LL + lane] = (float)myv;
}

extern "C" void kernel_launch(void* const* d_in, const int* in_sizes, int n_in,
                              void* d_out, int out_size, void* d_ws,
                              size_t ws_size, hipStream_t stream) {
  const float* feats = (const float*)d_in[0];
  const float* trans = (const float*)d_in[1];
  float* out = (float*)d_out;  // [0,1024): scores; then paths [B*T]

  unsigned char* bptr = (unsigned char*)d_ws;              // 50,331,648 B
  char* p = (char*)d_ws + (size_t)BB * TT * KK;
  int* bestArr = (int*)p;                                  // 4 KB
  p += BB * sizeof(int);
  unsigned char* cmap = (unsigned char*)p;                 // 786,432 B
  p += (size_t)BB * CC * KK;
  int* entry = (int*)p;                                    // 64 KB

  viterbi_fwd<<<dim3(BB), dim3(128), 0, stream>>>(feats, trans, out, bptr,
                                                  bestArr);
  bwd_map<<<dim3(BB * CC / 4), dim3(256), 0, stream>>>(bptr, cmap);
  bwd_entry<<<dim3(BB / 4), dim3(256), 0, stream>>>(cmap, bestArr, entry);
  bwd_emit<<<dim3(BB * CC / 4), dim3(256), 0, stream>>>(bptr, entry,
                                                        out + BB);
}

// Round 5
// 635.311 us; speedup vs baseline: 1.6239x; 1.6239x over previous
//
#include <hip/hip_runtime.h>
#include <float.h>

// Viterbi decode: B=1024, T=1024, K=48.
// MAIN PATH (needs 201MB ws): forward is max-only (no argmax): lane=next,
//   fv in registers, broadcast via v_readlane (no LDS), ~80 VALU/step.
//   Stores pre-feat max row mx_t (fp32, exact) per step.
// Backward: single chain kernel per b. path[j-1] = first p with
//   (mx_{j-1}[p]+feat_{j-1}[p]) + tr[tag][p] == mx_j[tag]  (bitwise exact:
//   fp max returns one of its inputs; adds re-executed with same operands).
//   Chain = ds_read(trans row) + add + cmp_eq + ballot + ff1. mx/feat rows
//   prefetched in 8-deep static rings.
// FALLBACK (ws < 201MB): R1 structure (argmax forward + 3-pass backward).

#define BB 1024
#define TT 1024
#define KK 48
#define CC 16
#define LL 64
#define NEGV -10000.0f

__device__ __forceinline__ float rdlane(float v, int l) {
  return __int_as_float(__builtin_amdgcn_readlane(__float_as_int(v), l));
}
__device__ __forceinline__ float max3f(float a, float b, float c) {
  return fmaxf(fmaxf(a, b), c);
}

// ---------------- main path ----------------

__global__ __launch_bounds__(64, 1) void viterbi_fwd_mx(
    const float* __restrict__ feats, const float* __restrict__ trans,
    float* __restrict__ scores, float* __restrict__ mx,
    int* __restrict__ bestArr) {
  const int lane = threadIdx.x;
  const int b = blockIdx.x;
  const int rl = (lane < KK) ? lane : (KK - 1);

  float tr[KK];
#pragma unroll
  for (int j = 0; j < 12; ++j) {
    float4 t4 = *(const float4*)(trans + rl * KK + 4 * j);
    tr[4 * j + 0] = t4.x; tr[4 * j + 1] = t4.y;
    tr[4 * j + 2] = t4.z; tr[4 * j + 3] = t4.w;
  }
  const float tstop = trans[(KK - 1) * KK + rl];

  const float* fp = feats + (size_t)b * TT * KK + rl;
  float* mp = mx + (size_t)b * TT * KK + rl;

  float fv = (lane == 46) ? 0.0f : NEGV;  // F_0 (lanes>=48 mirror lane47: NEG)

  float fbuf[4];
#pragma unroll
  for (int k = 0; k < 4; ++k) fbuf[k] = fp[(size_t)k * KK];

  for (int t0 = 0; t0 < TT; t0 += 4) {
#pragma unroll
    for (int u = 0; u < 4; ++u) {
      const int t = t0 + u;
      float part[16];
#pragma unroll
      for (int g = 0; g < 16; ++g) {
        float a0 = rdlane(fv, 3 * g + 0) + tr[3 * g + 0];
        float a1 = rdlane(fv, 3 * g + 1) + tr[3 * g + 1];
        float a2 = rdlane(fv, 3 * g + 2) + tr[3 * g + 2];
        part[g] = max3f(a0, a1, a2);
      }
      float q0 = max3f(part[0], part[1], part[2]);
      float q1 = max3f(part[3], part[4], part[5]);
      float q2 = max3f(part[6], part[7], part[8]);
      float q3 = max3f(part[9], part[10], part[11]);
      float q4 = max3f(part[12], part[13], part[14]);
      float m = fmaxf(max3f(q0, q1, q2), max3f(q3, q4, part[15]));
      // all 64 lanes store; lanes 48..63 duplicate lane47's addr+value (benign)
      mp[(size_t)t * KK] = m;
      float nf = m + fbuf[u];
      int tpre = t + 4; if (tpre >= TT) tpre = 0;
      fbuf[u] = fp[(size_t)tpre * KK];
      fv = nf;
    }
  }

  float v = (lane < KK) ? (fv + tstop) : -FLT_MAX;
  int idx = lane;
#pragma unroll
  for (int off = 32; off >= 1; off >>= 1) {
    float ov = __shfl_xor(v, off);
    int oi = __shfl_xor(idx, off);
    bool take = (ov > v) || (ov == v && oi < idx);
    v = take ? ov : v;
    idx = take ? oi : idx;
  }
  if (lane == 0) { scores[b] = v; bestArr[b] = idx; }
}

__global__ __launch_bounds__(64, 1) void viterbi_bwd_mx(
    const float* __restrict__ feats, const float* __restrict__ trans,
    const float* __restrict__ mx, const int* __restrict__ bestArr,
    float* __restrict__ path) {
  __shared__ float tl[KK * KK];
  const int lane = threadIdx.x;
  const int b = blockIdx.x;
  const int rl = (lane < KK) ? lane : (KK - 1);
  for (int i = lane; i < KK * KK; i += 64) tl[i] = trans[i];
  __syncthreads();

  const float* fp = feats + (size_t)b * TT * KK + rl;
  const float* mp = mx + (size_t)b * TT * KK + rl;
  int tag = bestArr[b];  // wave-uniform

  // ring slot u (within a block of 8 descending j): A[u]=mx_j, Bv[u]=feat_{j-1}
  float A[8], Bv[8];
#pragma unroll
  for (int k = 0; k < 8; ++k) {
    int j = TT - 1 - k;
    A[k] = mp[(size_t)j * KK];
    int jm = j - 1; if (jm < 0) jm = 0;
    Bv[k] = fp[(size_t)jm * KK];
  }

  int myv = 0;  // lane (j&63) holds path[j]
  for (int jb = TT - 1; jb >= 0; jb -= 8) {
#pragma unroll
    for (int u = 0; u < 8; ++u) {
      const int j = jb - u;
      if (lane == (j & 63)) myv = tag;  // path[j] = tag (before update)
      if ((j & 63) == 0) {
        path[(size_t)b * TT + j + lane] = (float)myv;
      }
      if (j > 0) {
        float target = rdlane(A[u], tag);            // mx_j[tag]
        float F = A[(u + 1) & 7] + Bv[u];            // F_j[p]=mx_{j-1}+feat_{j-1}
        float s = F + tl[tag * KK + rl];             // + tr[tag][p]
        bool eq = (lane < KK) && (s == target);
        unsigned long long bal = __ballot(eq);       // nonzero by construction
        tag = __ffsll((long long)bal) - 1;           // first p (np.argmax tie)
      }
      // refill slot u for the next block (rows jb-8-u and jb-8-u-1), clamped
      int jn = jb - 8 - u;
      int jc = jn < 0 ? 0 : jn;
      A[u] = mp[(size_t)jc * KK];
      int jm2 = jc - 1; if (jm2 < 0) jm2 = 0;
      Bv[u] = fp[(size_t)jm2 * KK];
    }
  }
}

// ---------------- fallback path (R1) ----------------

__global__ __launch_bounds__(64, 1) void viterbi_fwd_f(
    const float* __restrict__ feats, const float* __restrict__ trans,
    float* __restrict__ scores, unsigned char* __restrict__ bptr,
    int* __restrict__ bestArr) {
  __shared__ __align__(16) float fvbuf[64];
  const int lane = threadIdx.x;
  const int b = blockIdx.x;
  const int rl = (lane < KK) ? lane : (KK - 1);

  float tr[KK];
#pragma unroll
  for (int j = 0; j < 12; ++j) {
    float4 t4 = *(const float4*)(trans + rl * KK + 4 * j);
    tr[4 * j + 0] = t4.x; tr[4 * j + 1] = t4.y;
    tr[4 * j + 2] = t4.z; tr[4 * j + 3] = t4.w;
  }
  const float tstop = trans[(KK - 1) * KK + rl];

  if (lane < KK) fvbuf[lane] = (lane == 46) ? 0.0f : NEGV;
  __builtin_amdgcn_wave_barrier();

  const float* fp = feats + (size_t)b * TT * KK + rl;
  unsigned char* bp = bptr + (size_t)b * TT * KK + lane;

  float fbuf[4];
#pragma unroll
  for (int k = 0; k < 4; ++k) fbuf[k] = fp[(size_t)k * KK];

  float fv = NEGV;
  for (int t0 = 0; t0 < TT; t0 += 4) {
#pragma unroll
    for (int u = 0; u < 4; ++u) {
      const int t = t0 + u;
      float fvr[KK];
#pragma unroll
      for (int j = 0; j < 12; ++j) {
        float4 v4 = *(const float4*)(&fvbuf[4 * j]);
        fvr[4 * j + 0] = v4.x; fvr[4 * j + 1] = v4.y;
        fvr[4 * j + 2] = v4.z; fvr[4 * j + 3] = v4.w;
      }
      __builtin_amdgcn_wave_barrier();

      float bs0 = fvr[0] + tr[0], bs1 = fvr[12] + tr[12];
      float bs2 = fvr[24] + tr[24], bs3 = fvr[36] + tr[36];
      int bi0 = 0, bi1 = 12, bi2 = 24, bi3 = 36;
#pragma unroll
      for (int p = 1; p < 12; ++p) {
        float s0 = fvr[p] + tr[p];
        float s1 = fvr[12 + p] + tr[12 + p];
        float s2 = fvr[24 + p] + tr[24 + p];
        float s3 = fvr[36 + p] + tr[36 + p];
        if (s0 > bs0) { bs0 = s0; bi0 = p; }
        if (s1 > bs1) { bs1 = s1; bi1 = 12 + p; }
        if (s2 > bs2) { bs2 = s2; bi2 = 24 + p; }
        if (s3 > bs3) { bs3 = s3; bi3 = 36 + p; }
      }
      bool c1 = bs1 > bs0;
      float m01 = c1 ? bs1 : bs0; int i01 = c1 ? bi1 : bi0;
      bool c3 = bs3 > bs2;
      float m23 = c3 ? bs3 : bs2; int i23 = c3 ? bi3 : bi2;
      bool cf = m23 > m01;
      float m = cf ? m23 : m01; int bpi = cf ? i23 : i01;

      float nfv = m + fbuf[u];
      int tpre = t + 4; if (tpre >= TT) tpre = 0;
      fbuf[u] = fp[(size_t)tpre * KK];

      if (lane < KK) {
        bp[(size_t)t * KK] = (unsigned char)bpi;
        fvbuf[lane] = nfv;
        fv = nfv;
      }
      __builtin_amdgcn_wave_barrier();
    }
  }

  float v = (lane < KK) ? (fv + tstop) : -FLT_MAX;
  int idx = lane;
#pragma unroll
  for (int off = 32; off >= 1; off >>= 1) {
    float ov = __shfl_xor(v, off);
    int oi = __shfl_xor(idx, off);
    bool take = (ov > v) || (ov == v && oi < idx);
    v = take ? ov : v;
    idx = take ? oi : idx;
  }
  if (lane == 0) { scores[b] = v; bestArr[b] = idx; }
}

__global__ __launch_bounds__(256) void bwd_map(
    const unsigned char* __restrict__ bptr, unsigned char* __restrict__ cmap) {
  const int lane = threadIdx.x & 63;
  const int wg = blockIdx.x * 4 + (threadIdx.x >> 6);
  const int b = wg >> 4;
  const int c = wg & (CC - 1);
  const int rl = (lane < KK) ? lane : (KK - 1);
  const unsigned char* bp = bptr + ((size_t)b * TT + (size_t)c * LL) * KK + rl;

  int x = rl;
  const int CH = 16;
  int cur[CH], nxt[CH];
#pragma unroll
  for (int j = 0; j < CH; ++j) cur[j] = bp[(size_t)(LL - CH + j) * KK];
  for (int tb = LL - CH; tb >= 0; tb -= CH) {
    if (tb >= CH) {
#pragma unroll
      for (int j = 0; j < CH; ++j) nxt[j] = bp[(size_t)(tb - CH + j) * KK];
    }
#pragma unroll
    for (int j = CH - 1; j >= 0; --j) x = __shfl(cur[j], x);
    if (tb >= CH) {
#pragma unroll
      for (int j = 0; j < CH; ++j) cur[j] = nxt[j];
    }
  }
  if (lane < KK) cmap[(size_t)wg * KK + lane] = (unsigned char)x;
}

__global__ __launch_bounds__(256) void bwd_entry(
    const unsigned char* __restrict__ cmap, const int* __restrict__ bestArr,
    int* __restrict__ entry) {
  const int lane = threadIdx.x & 63;
  const int b = blockIdx.x * 4 + (threadIdx.x >> 6);
  const int rl = (lane < KK) ? lane : (KK - 1);

  int rows[CC];
#pragma unroll
  for (int c = 0; c < CC; ++c) rows[c] = cmap[((size_t)b * CC + c) * KK + rl];

  int tag = bestArr[b];
  int ev = 0;
#pragma unroll
  for (int c = CC - 1; c >= 0; --c) {
    if (lane == c) ev = tag;
    tag = __shfl(rows[c], tag);
  }
  if (lane < CC) entry[b * CC + lane] = ev;
}

__global__ __launch_bounds__(256) void bwd_emit(
    const unsigned char* __restrict__ bptr, const int* __restrict__ entry,
    float* __restrict__ path) {
  const int lane = threadIdx.x & 63;
  const int wg = blockIdx.x * 4 + (threadIdx.x >> 6);
  const int b = wg >> 4;
  const int c = wg & (CC - 1);
  const int rl = (lane < KK) ? lane : (KK - 1);
  const unsigned char* bp = bptr + ((size_t)b * TT + (size_t)c * LL) * KK + rl;

  int x = entry[b * CC + c];
  int myv = 0;
  const int CH = 16;
  int cur[CH], nxt[CH];
#pragma unroll
  for (int j = 0; j < CH; ++j) cur[j] = bp[(size_t)(LL - CH + j) * KK];
  for (int tb = LL - CH; tb >= 0; tb -= CH) {
    if (tb >= CH) {
#pragma unroll
      for (int j = 0; j < CH; ++j) nxt[j] = bp[(size_t)(tb - CH + j) * KK];
    }
#pragma unroll
    for (int j = CH - 1; j >= 0; --j) {
      if (lane == tb + j) myv = x;
      x = __shfl(cur[j], x);
    }
    if (tb >= CH) {
#pragma unroll
      for (int j = 0; j < CH; ++j) cur[j] = nxt[j];
    }
  }
  path[(size_t)b * TT + (size_t)c * LL + lane] = (float)myv;
}

extern "C" void kernel_launch(void* const* d_in, const int* in_sizes, int n_in,
                              void* d_out, int out_size, void* d_ws,
                              size_t ws_size, hipStream_t stream) {
  const float* feats = (const float*)d_in[0];
  const float* trans = (const float*)d_in[1];
  float* out = (float*)d_out;  // [0,1024): scores; then paths [B*T]

  const size_t MX_BYTES = (size_t)BB * TT * KK * sizeof(float);  // 201.3 MB
  if (ws_size >= MX_BYTES + 4096) {
    float* mx = (float*)d_ws;
    int* bestArr = (int*)((char*)d_ws + MX_BYTES);
    viterbi_fwd_mx<<<dim3(BB), dim3(64), 0, stream>>>(feats, trans, out, mx,
                                                      bestArr);
    viterbi_bwd_mx<<<dim3(BB), dim3(64), 0, stream>>>(feats, trans, mx,
                                                      bestArr, out + BB);
  } else {
    unsigned char* bptr = (unsigned char*)d_ws;
    char* p = (char*)d_ws + (size_t)BB * TT * KK;
    int* bestArr = (int*)p;
    p += BB * sizeof(int);
    unsigned char* cmap = (unsigned char*)p;
    p += (size_t)BB * CC * KK;
    int* entry = (int*)p;

    viterbi_fwd_f<<<dim3(BB), dim3(64), 0, stream>>>(feats, trans, out, bptr,
                                                     bestArr);
    bwd_map<<<dim3(BB * CC / 4), dim3(256), 0, stream>>>(bptr, cmap);
    bwd_entry<<<dim3(BB / 4), dim3(256), 0, stream>>>(cmap, bestArr, entry);
    bwd_emit<<<dim3(BB * CC / 4), dim3(256), 0, stream>>>(bptr, entry,
                                                          out + BB);
  }
}

// Round 6
// 533.879 us; speedup vs baseline: 1.9324x; 1.1900x over previous
//
#include <hip/hip_runtime.h>
#include <float.h>

// Viterbi decode: B=1024, T=1024, K=48.
// fwd: max-only recurrence, lane=next. fv broadcast via batched readlanes,
//   tr pinned in regs, feat rows double-buffered in blocks of 8 (bulk loads
//   -> amortized vmcnt). Stores pre-feat max row mx_t (exact fp32).
// bwd: equality backtrack. mx/feat rows bulk-loaded in blocks of 8 with
//   ping-pong buffers (single waitcnt per block, not per step). Vote:
//   s = F + tr_row == mx_j[tag] -> ballot -> ctz (first index == np.argmax).
// FALLBACK (ws < 201MB): R1 structure.

#define BB 1024
#define TT 1024
#define KK 48
#define CC 16
#define LL 64
#define NEGV -10000.0f

__device__ __forceinline__ float rdlane(float v, int l) {
  return __int_as_float(__builtin_amdgcn_readlane(__float_as_int(v), l));
}
__device__ __forceinline__ float max3f(float a, float b, float c) {
  return fmaxf(fmaxf(a, b), c);
}

// ---------------- main path ----------------

#define FSTEP(T_, FEAT_)                                                   \
  {                                                                        \
    float fvs[KK];                                                         \
    _Pragma("unroll") for (int p = 0; p < KK; ++p) {                       \
      fvs[p] = rdlane(fv, p);                                              \
    }                                                                      \
    float s_[KK];                                                          \
    _Pragma("unroll") for (int p = 0; p < KK; ++p) {                       \
      s_[p] = fvs[p] + tr[p];                                              \
    }                                                                      \
    float part[16];                                                        \
    _Pragma("unroll") for (int g = 0; g < 16; ++g) {                       \
      part[g] = max3f(s_[3 * g], s_[3 * g + 1], s_[3 * g + 2]);            \
    }                                                                      \
    float q0 = max3f(part[0], part[1], part[2]);                           \
    float q1 = max3f(part[3], part[4], part[5]);                           \
    float q2 = max3f(part[6], part[7], part[8]);                           \
    float q3 = max3f(part[9], part[10], part[11]);                         \
    float q4 = max3f(part[12], part[13], part[14]);                        \
    float m_ = fmaxf(max3f(q0, q1, q2), max3f(q3, q4, part[15]));          \
    mp[(size_t)(T_)*KK] = m_;                                              \
    fv = m_ + (FEAT_);                                                     \
  }

__global__ __launch_bounds__(64, 1) void viterbi_fwd_mx(
    const float* __restrict__ feats, const float* __restrict__ trans,
    float* __restrict__ scores, float* __restrict__ mx,
    int* __restrict__ bestArr) {
  const int lane = threadIdx.x;
  const int b = blockIdx.x;
  const int rl = (lane < KK) ? lane : (KK - 1);

  float tr[KK];
#pragma unroll
  for (int j = 0; j < 12; ++j) {
    float4 t4 = *(const float4*)(trans + rl * KK + 4 * j);
    tr[4 * j + 0] = t4.x; tr[4 * j + 1] = t4.y;
    tr[4 * j + 2] = t4.z; tr[4 * j + 3] = t4.w;
  }
  // pin: block rematerialization / spilling-to-memory of the transition row
#pragma unroll
  for (int j = 0; j < KK; ++j) asm volatile("" : "+v"(tr[j]));
  const float tstop = trans[(KK - 1) * KK + rl];

  const float* fp = feats + (size_t)b * TT * KK + rl;
  float* mp = mx + (size_t)b * TT * KK + rl;

  float fv = (lane == 46) ? 0.0f : NEGV;  // F_0

  float fA[8], fB[8];
#pragma unroll
  for (int k = 0; k < 8; ++k) fA[k] = fp[(size_t)k * KK];

  for (int t0 = 0; t0 < TT; t0 += 16) {
    // bulk prefetch rows t0+8..t0+15 into fB
#pragma unroll
    for (int k = 0; k < 8; ++k)
      fB[k] = fp[(size_t)((t0 + 8 + k) & (TT - 1)) * KK];
#pragma unroll
    for (int u = 0; u < 8; ++u) FSTEP(t0 + u, fA[u]);
    // bulk prefetch rows t0+16..t0+23 into fA
#pragma unroll
    for (int k = 0; k < 8; ++k)
      fA[k] = fp[(size_t)((t0 + 16 + k) & (TT - 1)) * KK];
#pragma unroll
    for (int u = 0; u < 8; ++u) FSTEP(t0 + 8 + u, fB[u]);
  }

  float v = (lane < KK) ? (fv + tstop) : -FLT_MAX;
  int idx = lane;
#pragma unroll
  for (int off = 32; off >= 1; off >>= 1) {
    float ov = __shfl_xor(v, off);
    int oi = __shfl_xor(idx, off);
    bool take = (ov > v) || (ov == v && oi < idx);
    v = take ? ov : v;
    idx = take ? oi : idx;
  }
  if (lane == 0) { scores[b] = v; bestArr[b] = idx; }
}

__global__ __launch_bounds__(64, 1) void viterbi_bwd_mx(
    const float* __restrict__ feats, const float* __restrict__ trans,
    const float* __restrict__ mx, const int* __restrict__ bestArr,
    float* __restrict__ path) {
  __shared__ float tl[KK * KK];
  const int lane = threadIdx.x;
  const int b = blockIdx.x;
  const int rl = (lane < KK) ? lane : (KK - 1);
  for (int i = lane; i < KK * KK; i += 64) tl[i] = trans[i];
  __syncthreads();

  const float* fp = feats + (size_t)b * TT * KK + rl;
  const float* mp = mx + (size_t)b * TT * KK + rl;
  int tag = bestArr[b];  // wave-uniform

  float topA = mp[(size_t)(TT - 1) * KK];  // mx_{T-1}
  float MA[8], FE[8], MB[8], FB2[8];
  // block jb=T-1 needs mx/feat rows jb-1-u (u=0..7)
#pragma unroll
  for (int u = 0; u < 8; ++u) {
    MA[u] = mp[(size_t)(TT - 2 - u) * KK];
    FE[u] = fp[(size_t)(TT - 2 - u) * KK];
  }

  int myv = 0;  // lane (j&63) holds path[j]
  for (int jb = TT - 1; jb >= 15; jb -= 16) {
    // bulk load block jb-8 (rows jb-9-u), clamped
#pragma unroll
    for (int u = 0; u < 8; ++u) {
      int r = jb - 9 - u; int rc = r < 0 ? 0 : r;
      MB[u] = mp[(size_t)rc * KK];
      FB2[u] = fp[(size_t)rc * KK];
    }
    // process block jb with topA / MA / FE
#pragma unroll
    for (int u = 0; u < 8; ++u) {
      const int j = jb - u;
      if (lane == (j & 63)) myv = tag;
      if ((j & 63) == 0) path[(size_t)b * TT + j + lane] = (float)myv;
      float Tg = (u == 0) ? topA : MA[u - 1];
      float target = rdlane(Tg, tag);            // mx_j[tag]
      float s = (MA[u] + FE[u]) + tl[tag * KK + rl];
      unsigned long long bal = __ballot(s == target);  // lanes>=48 mirror 47
      tag = (int)__builtin_ctzll(bal);           // first p (np.argmax tie)
    }
    float topB = MA[7];  // mx_{jb-8}
    // bulk load block jb-16 (rows jb-17-u), clamped
#pragma unroll
    for (int u = 0; u < 8; ++u) {
      int r = jb - 17 - u; int rc = r < 0 ? 0 : r;
      MA[u] = mp[(size_t)rc * KK];
      FE[u] = fp[(size_t)rc * KK];
    }
    // process block jb-8 with topB / MB / FB2
#pragma unroll
    for (int u = 0; u < 8; ++u) {
      const int j = jb - 8 - u;
      if (lane == (j & 63)) myv = tag;
      if ((j & 63) == 0) path[(size_t)b * TT + j + lane] = (float)myv;
      float Tg = (u == 0) ? topB : MB[u - 1];
      float target = rdlane(Tg, tag);
      float s = (MB[u] + FB2[u]) + tl[tag * KK + rl];
      unsigned long long bal = __ballot(s == target);
      tag = (int)__builtin_ctzll(bal);  // garbage after j==0 vote: unused
    }
    topA = MB[7];
  }
}

// ---------------- fallback path (R1) ----------------

__global__ __launch_bounds__(64, 1) void viterbi_fwd_f(
    const float* __restrict__ feats, const float* __restrict__ trans,
    float* __restrict__ scores, unsigned char* __restrict__ bptr,
    int* __restrict__ bestArr) {
  __shared__ __align__(16) float fvbuf[64];
  const int lane = threadIdx.x;
  const int b = blockIdx.x;
  const int rl = (lane < KK) ? lane : (KK - 1);

  float tr[KK];
#pragma unroll
  for (int j = 0; j < 12; ++j) {
    float4 t4 = *(const float4*)(trans + rl * KK + 4 * j);
    tr[4 * j + 0] = t4.x; tr[4 * j + 1] = t4.y;
    tr[4 * j + 2] = t4.z; tr[4 * j + 3] = t4.w;
  }
  const float tstop = trans[(KK - 1) * KK + rl];

  if (lane < KK) fvbuf[lane] = (lane == 46) ? 0.0f : NEGV;
  __builtin_amdgcn_wave_barrier();

  const float* fp = feats + (size_t)b * TT * KK + rl;
  unsigned char* bp = bptr + (size_t)b * TT * KK + lane;

  float fbuf[4];
#pragma unroll
  for (int k = 0; k < 4; ++k) fbuf[k] = fp[(size_t)k * KK];

  float fv = NEGV;
  for (int t0 = 0; t0 < TT; t0 += 4) {
#pragma unroll
    for (int u = 0; u < 4; ++u) {
      const int t = t0 + u;
      float fvr[KK];
#pragma unroll
      for (int j = 0; j < 12; ++j) {
        float4 v4 = *(const float4*)(&fvbuf[4 * j]);
        fvr[4 * j + 0] = v4.x; fvr[4 * j + 1] = v4.y;
        fvr[4 * j + 2] = v4.z; fvr[4 * j + 3] = v4.w;
      }
      __builtin_amdgcn_wave_barrier();

      float bs0 = fvr[0] + tr[0], bs1 = fvr[12] + tr[12];
      float bs2 = fvr[24] + tr[24], bs3 = fvr[36] + tr[36];
      int bi0 = 0, bi1 = 12, bi2 = 24, bi3 = 36;
#pragma unroll
      for (int p = 1; p < 12; ++p) {
        float s0 = fvr[p] + tr[p];
        float s1 = fvr[12 + p] + tr[12 + p];
        float s2 = fvr[24 + p] + tr[24 + p];
        float s3 = fvr[36 + p] + tr[36 + p];
        if (s0 > bs0) { bs0 = s0; bi0 = p; }
        if (s1 > bs1) { bs1 = s1; bi1 = 12 + p; }
        if (s2 > bs2) { bs2 = s2; bi2 = 24 + p; }
        if (s3 > bs3) { bs3 = s3; bi3 = 36 + p; }
      }
      bool c1 = bs1 > bs0;
      float m01 = c1 ? bs1 : bs0; int i01 = c1 ? bi1 : bi0;
      bool c3 = bs3 > bs2;
      float m23 = c3 ? bs3 : bs2; int i23 = c3 ? bi3 : bi2;
      bool cf = m23 > m01;
      float m = cf ? m23 : m01; int bpi = cf ? i23 : i01;

      float nfv = m + fbuf[u];
      int tpre = t + 4; if (tpre >= TT) tpre = 0;
      fbuf[u] = fp[(size_t)tpre * KK];

      if (lane < KK) {
        bp[(size_t)t * KK] = (unsigned char)bpi;
        fvbuf[lane] = nfv;
        fv = nfv;
      }
      __builtin_amdgcn_wave_barrier();
    }
  }

  float v = (lane < KK) ? (fv + tstop) : -FLT_MAX;
  int idx = lane;
#pragma unroll
  for (int off = 32; off >= 1; off >>= 1) {
    float ov = __shfl_xor(v, off);
    int oi = __shfl_xor(idx, off);
    bool take = (ov > v) || (ov == v && oi < idx);
    v = take ? ov : v;
    idx = take ? oi : idx;
  }
  if (lane == 0) { scores[b] = v; bestArr[b] = idx; }
}

__global__ __launch_bounds__(256) void bwd_map(
    const unsigned char* __restrict__ bptr, unsigned char* __restrict__ cmap) {
  const int lane = threadIdx.x & 63;
  const int wg = blockIdx.x * 4 + (threadIdx.x >> 6);
  const int b = wg >> 4;
  const int c = wg & (CC - 1);
  const int rl = (lane < KK) ? lane : (KK - 1);
  const unsigned char* bp = bptr + ((size_t)b * TT + (size_t)c * LL) * KK + rl;

  int x = rl;
  const int CH = 16;
  int cur[CH], nxt[CH];
#pragma unroll
  for (int j = 0; j < CH; ++j) cur[j] = bp[(size_t)(LL - CH + j) * KK];
  for (int tb = LL - CH; tb >= 0; tb -= CH) {
    if (tb >= CH) {
#pragma unroll
      for (int j = 0; j < CH; ++j) nxt[j] = bp[(size_t)(tb - CH + j) * KK];
    }
#pragma unroll
    for (int j = CH - 1; j >= 0; --j) x = __shfl(cur[j], x);
    if (tb >= CH) {
#pragma unroll
      for (int j = 0; j < CH; ++j) cur[j] = nxt[j];
    }
  }
  if (lane < KK) cmap[(size_t)wg * KK + lane] = (unsigned char)x;
}

__global__ __launch_bounds__(256) void bwd_entry(
    const unsigned char* __restrict__ cmap, const int* __restrict__ bestArr,
    int* __restrict__ entry) {
  const int lane = threadIdx.x & 63;
  const int b = blockIdx.x * 4 + (threadIdx.x >> 6);
  const int rl = (lane < KK) ? lane : (KK - 1);

  int rows[CC];
#pragma unroll
  for (int c = 0; c < CC; ++c) rows[c] = cmap[((size_t)b * CC + c) * KK + rl];

  int tag = bestArr[b];
  int ev = 0;
#pragma unroll
  for (int c = CC - 1; c >= 0; --c) {
    if (lane == c) ev = tag;
    tag = __shfl(rows[c], tag);
  }
  if (lane < CC) entry[b * CC + lane] = ev;
}

__global__ __launch_bounds__(256) void bwd_emit(
    const unsigned char* __restrict__ bptr, const int* __restrict__ entry,
    float* __restrict__ path) {
  const int lane = threadIdx.x & 63;
  const int wg = blockIdx.x * 4 + (threadIdx.x >> 6);
  const int b = wg >> 4;
  const int c = wg & (CC - 1);
  const int rl = (lane < KK) ? lane : (KK - 1);
  const unsigned char* bp = bptr + ((size_t)b * TT + (size_t)c * LL) * KK + rl;

  int x = entry[b * CC + c];
  int myv = 0;
  const int CH = 16;
  int cur[CH], nxt[CH];
#pragma unroll
  for (int j = 0; j < CH; ++j) cur[j] = bp[(size_t)(LL - CH + j) * KK];
  for (int tb = LL - CH; tb >= 0; tb -= CH) {
    if (tb >= CH) {
#pragma unroll
      for (int j = 0; j < CH; ++j) nxt[j] = bp[(size_t)(tb - CH + j) * KK];
    }
#pragma unroll
    for (int j = CH - 1; j >= 0; --j) {
      if (lane == tb + j) myv = x;
      x = __shfl(cur[j], x);
    }
    if (tb >= CH) {
#pragma unroll
      for (int j = 0; j < CH; ++j) cur[j] = nxt[j];
    }
  }
  path[(size_t)b * TT + (size_t)c * LL + lane] = (float)myv;
}

extern "C" void kernel_launch(void* const* d_in, const int* in_sizes, int n_in,
                              void* d_out, int out_size, void* d_ws,
                              size_t ws_size, hipStream_t stream) {
  const float* feats = (const float*)d_in[0];
  const float* trans = (const float*)d_in[1];
  float* out = (float*)d_out;  // [0,1024): scores; then paths [B*T]

  const size_t MX_BYTES = (size_t)BB * TT * KK * sizeof(float);  // 201.3 MB
  if (ws_size >= MX_BYTES + 4096) {
    float* mx = (float*)d_ws;
    int* bestArr = (int*)((char*)d_ws + MX_BYTES);
    viterbi_fwd_mx<<<dim3(BB), dim3(64), 0, stream>>>(feats, trans, out, mx,
                                                      bestArr);
    viterbi_bwd_mx<<<dim3(BB), dim3(64), 0, stream>>>(feats, trans, mx,
                                                      bestArr, out + BB);
  } else {
    unsigned char* bptr = (unsigned char*)d_ws;
    char* p = (char*)d_ws + (size_t)BB * TT * KK;
    int* bestArr = (int*)p;
    p += BB * sizeof(int);
    unsigned char* cmap = (unsigned char*)p;
    p += (size_t)BB * CC * KK;
    int* entry = (int*)p;

    viterbi_fwd_f<<<dim3(BB), dim3(64), 0, stream>>>(feats, trans, out, bptr,
                                                     bestArr);
    bwd_map<<<dim3(BB * CC / 4), dim3(256), 0, stream>>>(bptr, cmap);
    bwd_entry<<<dim3(BB / 4), dim3(256), 0, stream>>>(cmap, bestArr, entry);
    bwd_emit<<<dim3(BB * CC / 4), dim3(256), 0, stream>>>(bptr, entry,
                                                          out + BB);
  }
}